// Round 5
// baseline (625.303 us; speedup 1.0000x reference)
//
#include <hip/hip_runtime.h>
#include <stdint.h>

#define NTOK 4096   // B*S tokens
#define DIM  1024   // model dim
#define NEXP 8      // experts
#define HID  4096   // expert hidden
#define CAP  1024   // capacity per expert

typedef __bf16 bf16x8 __attribute__((ext_vector_type(8)));
typedef float  f32x4  __attribute__((ext_vector_type(4)));

__device__ __forceinline__ unsigned short f2bf(float f) {
  unsigned int u = __float_as_uint(f);
  return (unsigned short)((u + 0x7fffu + ((u >> 16) & 1u)) >> 16);  // RNE
}

__device__ __forceinline__ float bf2f(unsigned int bits16) {
  return __uint_as_float(bits16 << 16);
}

// pack two fp32 -> two bf16 (truncation) in ONE v_perm_b32:
// result = (hi16(b) << 16) | hi16(a)
__device__ __forceinline__ unsigned packbf(float a, float b) {
  return __builtin_amdgcn_perm(__float_as_uint(b), __float_as_uint(a), 0x07060302);
}

__device__ __forceinline__ void load_lds16(const void* g, void* l) {
  __builtin_amdgcn_global_load_lds(
      (__attribute__((address_space(1))) void*)g,
      (__attribute__((address_space(3))) void*)l,
      16, 0, 0);
}

// ---------------- 1. gating: fp32 exact (expert choice must match reference) ----
__global__ void gating_kernel(const float* __restrict__ x, const float* __restrict__ wg,
                              int* __restrict__ tok_e, float* __restrict__ tok_g) {
  const int t = blockIdx.x;
  const int l = threadIdx.x;
  float acc[NEXP];
#pragma unroll
  for (int e = 0; e < NEXP; ++e) acc[e] = 0.f;

  const float4* x4  = (const float4*)(x + (size_t)t * DIM);
  const float4* wg4 = (const float4*)wg;
#pragma unroll
  for (int i = 0; i < 4; ++i) {
    int dq = i * 64 + l;
    float4 xv = x4[dq];
    float xs[4] = {xv.x, xv.y, xv.z, xv.w};
#pragma unroll
    for (int c = 0; c < 4; ++c) {
      int d = dq * 4 + c;
      float4 wa = wg4[d * 2], wb = wg4[d * 2 + 1];
      acc[0] += xs[c] * wa.x; acc[1] += xs[c] * wa.y;
      acc[2] += xs[c] * wa.z; acc[3] += xs[c] * wa.w;
      acc[4] += xs[c] * wb.x; acc[5] += xs[c] * wb.y;
      acc[6] += xs[c] * wb.z; acc[7] += xs[c] * wb.w;
    }
  }
#pragma unroll
  for (int off = 32; off; off >>= 1)
#pragma unroll
    for (int e = 0; e < NEXP; ++e) acc[e] += __shfl_xor(acc[e], off);

  if (l == 0) {
    float m = acc[0];
#pragma unroll
    for (int e = 1; e < NEXP; ++e) m = fmaxf(m, acc[e]);
    float p[NEXP];
#pragma unroll
    for (int e = 0; e < NEXP; ++e) p[e] = __expf(acc[e] - m);
    int e0 = 0; float b0 = p[0];
#pragma unroll
    for (int e = 1; e < NEXP; ++e) if (p[e] > b0) { b0 = p[e]; e0 = e; }
    int e1 = -1; float b1v = -1.f;
#pragma unroll
    for (int e = 0; e < NEXP; ++e) if (e != e0 && p[e] > b1v) { b1v = p[e]; e1 = e; }
    float inv = 1.f / (b0 + b1v);
    tok_e[2 * t] = e0; tok_e[2 * t + 1] = e1;
    tok_g[2 * t] = b0 * inv; tok_g[2 * t + 1] = b1v * inv;
  }
}

// ---------------- 2. GShard slot-major cumsum, 4-wave 2-phase ----------------
// entry order g = k*T + t. Wave w owns g in [w*2048, w*2048+2048).
__global__ void scan_kernel(const int* __restrict__ tok_e, int* __restrict__ tok_loc,
                            int* __restrict__ slot_map) {
  __shared__ int wcnt[4][NEXP];
  const int tid = threadIdx.x;
  const int w = tid >> 6, l = tid & 63;
  const unsigned long long below = (1ull << l) - 1ull;
  const int g0 = w * 2048;

  // phase 1: per-wave expert histogram
  int cnt[NEXP];
#pragma unroll
  for (int e = 0; e < NEXP; ++e) cnt[e] = 0;
  for (int it = 0; it < 32; ++it) {
    int g = g0 + it * 64 + l;
    int e = tok_e[(g & (NTOK - 1)) * 2 + (g >> 12)];
#pragma unroll
    for (int ex = 0; ex < NEXP; ++ex)
      cnt[ex] += __popcll(__ballot(e == ex));
  }
  if (l == 0)
#pragma unroll
    for (int e = 0; e < NEXP; ++e) wcnt[w][e] = cnt[e];
  __syncthreads();

  // phase 2: per-wave exclusive base
  int base[NEXP];
#pragma unroll
  for (int e = 0; e < NEXP; ++e) {
    int b = 0;
    for (int w2 = 0; w2 < 4; ++w2) if (w2 < w) b += wcnt[w2][e];
    base[e] = b;
  }
  // phase 3: locations
  for (int it = 0; it < 32; ++it) {
    int g = g0 + it * 64 + l;
    int e = tok_e[(g & (NTOK - 1)) * 2 + (g >> 12)];
    int loc = 0;
#pragma unroll
    for (int ex = 0; ex < NEXP; ++ex) {
      unsigned long long msk = __ballot(e == ex);
      int off = __popcll(msk & below);
      if (e == ex) loc = base[ex] + off;
      base[ex] += __popcll(msk);
    }
    int k = g >> 12, t = g & (NTOK - 1);
    bool valid = loc < CAP;
    tok_loc[t * 2 + k] = valid ? loc : -1;
    if (valid) slot_map[e * CAP + loc] = t;
  }
  // tail fill (disjoint from phase-3 writes)
#pragma unroll
  for (int ex = 0; ex < NEXP; ++ex) {
    int tot = wcnt[0][ex] + wcnt[1][ex] + wcnt[2][ex] + wcnt[3][ex];
    int c = tot < CAP ? tot : CAP;
    for (int i = c + tid; i < CAP; i += 256) slot_map[ex * CAP + i] = -1;
  }
}

// ---------------- 3. GEMM1 (fused dispatch): h = relu(gather(x) @ w1 + b1) ------
// A: gathered from x fp32 [T][D] via slot_map, cvt->bf16 into LDS [m][72-stride]
// B: w1 fp32 [K=D][N=H], transposed+cvt into LDS [n][88-stride]
// C: h bf16 [CAP][HID] per expert
template <int MB, int NB>
__global__ __launch_bounds__(256)
void gemm1_kernel(const float* __restrict__ X, const int* __restrict__ slot_map,
                  const float* __restrict__ W1, const float* __restrict__ b1,
                  unsigned short* __restrict__ Hout) {
  constexpr int M = CAP, N = HID, K = DIM;
  const int bid = blockIdx.x;
  const int e = bid / (MB * NB);
  const int r = bid - e * (MB * NB);
  const int patch = r / (MB * 4);
  const int q = r - patch * (MB * 4);
  const int m0 = (q >> 2) * 128;
  const int n0 = (patch * 4 + (q & 3)) * 128;

  const float* B = W1 + (size_t)e * K * N;
  const float* bias = b1 + (size_t)e * N;
  unsigned short* C = Hout + (size_t)e * M * N;

  const int tid = threadIdx.x;
  const int wave = tid >> 6, lane = tid & 63;
  const int wm = wave >> 1, wn = wave & 1;

  __shared__ __align__(16) unsigned short As[128 * 72];
  __shared__ __align__(16) unsigned short Bs[128 * 88];

  // A gather: thread covers row tid>>1 (of 128), k-half tid&1 (32 fp32)
  const int arow_s = tid >> 1;
  const int akh = tid & 1;
  const int t = slot_map[e * CAP + m0 + arow_s];
  const float* aPtr = X + (size_t)(t < 0 ? 0 : t) * DIM + akh * 32;
  const bool aValid = (t >= 0);
  // B: lane covers n = 4*(l&31), k = 16*wave + 8*(l>>5) + p
  const int bn = 4 * (lane & 31);
  const int bkb = 16 * wave + 8 * (lane >> 5);
  const float* bPtr = B + (size_t)bkb * N + n0 + bn;

  f32x4 acc[4][4] = {};
  const int quad = lane >> 4;
  const int arowb = (wm * 64 + (lane & 15)) * 72;
  const int browb = (wn * 64 + (lane & 15)) * 88;

  for (int it = 0; it < K / 64; ++it) {
    // global loads into regs (issue before barrier: overlaps prior MFMA tail)
    f32x4 fa[8], fb[8];
#pragma unroll
    for (int p = 0; p < 8; ++p) fa[p] = *(const f32x4*)(aPtr + p * 4);
#pragma unroll
    for (int p = 0; p < 8; ++p) fb[p] = *(const f32x4*)(bPtr + (size_t)p * N);
    aPtr += 64; bPtr += (size_t)64 * N;

    uint4 wa[4], wb[4];
#pragma unroll
    for (int i = 0; i < 4; ++i) {
      f32x4 f0 = fa[2 * i], f1 = fa[2 * i + 1];
      uint4 u;
      u.x = packbf(f0[0], f0[1]); u.y = packbf(f0[2], f0[3]);
      u.z = packbf(f1[0], f1[1]); u.w = packbf(f1[2], f1[3]);
      if (!aValid) { u.x = 0; u.y = 0; u.z = 0; u.w = 0; }
      wa[i] = u;
    }
#pragma unroll
    for (int j = 0; j < 4; ++j) {
      uint4 u;
      u.x = packbf(fb[0][j], fb[1][j]); u.y = packbf(fb[2][j], fb[3][j]);
      u.z = packbf(fb[4][j], fb[5][j]); u.w = packbf(fb[6][j], fb[7][j]);
      wb[j] = u;
    }

    __syncthreads();  // prior iter's LDS reads complete
#pragma unroll
    for (int i = 0; i < 4; ++i)
      *(uint4*)&As[arow_s * 72 + akh * 32 + i * 8] = wa[i];
#pragma unroll
    for (int j = 0; j < 4; ++j)
      *(uint4*)&Bs[(bn + j) * 88 + (bkb >> 3) * 8] = wb[j];
    __syncthreads();  // writes visible

#pragma unroll
    for (int kk = 0; kk < 64; kk += 32) {
      bf16x8 af[4], bfr[4];
#pragma unroll
      for (int i = 0; i < 4; ++i)
        af[i] = *reinterpret_cast<const bf16x8*>(&As[arowb + i * 16 * 72 + quad * 8 + kk]);
#pragma unroll
      for (int j = 0; j < 4; ++j)
        bfr[j] = *reinterpret_cast<const bf16x8*>(&Bs[browb + j * 16 * 88 + quad * 8 + kk]);
#pragma unroll
      for (int i = 0; i < 4; ++i)
#pragma unroll
        for (int j = 0; j < 4; ++j)
          acc[i][j] = __builtin_amdgcn_mfma_f32_16x16x32_bf16(af[i], bfr[j], acc[i][j], 0, 0, 0);
    }
  }

  // epilogue: 2-pass wave-private LDS restage -> coalesced dwordx4 stores
  __syncthreads();
  unsigned short* scr = (wave < 2 ? As : Bs) + (wave & 1) * 2304;
  const int lc = lane & 15;
  const int erow = lane >> 3;
  const int ecol = (lane & 7) * 8;
  unsigned short* Cbase = C + (size_t)(m0 + wm * 64) * N + n0 + wn * 64;
#pragma unroll
  for (int h2 = 0; h2 < 2; ++h2) {
#pragma unroll
    for (int j = 0; j < 4; ++j) {
      float bj = bias[n0 + wn * 64 + j * 16 + lc];
#pragma unroll
      for (int ii = 0; ii < 2; ++ii) {
        int i = h2 * 2 + ii;
#pragma unroll
        for (int rr = 0; rr < 4; ++rr) {
          float v = fmaxf(acc[i][j][rr] + bj, 0.f);
          scr[(ii * 16 + quad * 4 + rr) * 72 + j * 16 + lc] = f2bf(v);
        }
      }
    }
    __asm__ volatile("s_waitcnt lgkmcnt(0)" ::: "memory");
#pragma unroll
    for (int p = 0; p < 4; ++p) {
      uint4 v = *(const uint4*)&scr[(p * 8 + erow) * 72 + ecol];
      *(uint4*)&Cbase[(size_t)(h2 * 32 + p * 8 + erow) * N + ecol] = v;
    }
  }
}

// ---------------- 4. GEMM2: out = h @ w2 + b2 (bf16 out) ----------------
// A: h bf16 [M][K] via global_load_lds, dense XOR-swizzled LDS (R4 path)
// B: w2 fp32 [K=H][N=D], transposed+cvt into LDS [n][88-stride]
template <int MB, int NB>
__global__ __launch_bounds__(256)
void gemm2_kernel(const unsigned short* __restrict__ Hin, const float* __restrict__ W2,
                  const float* __restrict__ b2, unsigned short* __restrict__ Out) {
  constexpr int M = CAP, N = DIM, K = HID;
  const int bid = blockIdx.x;
  const int e = bid / (MB * NB);
  const int r = bid - e * (MB * NB);
  const int patch = r / (MB * 4);
  const int q = r - patch * (MB * 4);
  const int m0 = (q >> 2) * 128;
  const int n0 = (patch * 4 + (q & 3)) * 128;

  const unsigned short* A = Hin + (size_t)e * M * K;
  const float* B = W2 + (size_t)e * K * N;
  const float* bias = b2 + (size_t)e * N;
  unsigned short* C = Out + (size_t)e * M * N;

  const int tid = threadIdx.x;
  const int wave = tid >> 6, lane = tid & 63;
  const int wm = wave >> 1, wn = wave & 1;

  __shared__ __align__(16) unsigned short As[128 * 64];
  __shared__ __align__(16) unsigned short Bs[128 * 88];

  // A staging via DMA, XOR swizzle on global source column
  const int srow = lane >> 3;
  const int scol = ((lane & 7) ^ (srow & 7)) * 8;
  const unsigned short* gA = A + (size_t)(m0 + wave * 8 + srow) * K + scol;
  const int lbase = (wave * 8) * 64;
  // B: lane covers n = 4*(l&31), k = 16*wave + 8*(l>>5) + p
  const int bn = 4 * (lane & 31);
  const int bkb = 16 * wave + 8 * (lane >> 5);
  const float* bPtr = B + (size_t)bkb * N + n0 + bn;

  f32x4 acc[4][4] = {};
  const int quad = lane >> 4;
  const int lxor = lane & 7;
  const int arowb = (wm * 64 + (lane & 15)) * 64;
  const int browb = (wn * 64 + (lane & 15)) * 88;

  for (int it = 0; it < K / 64; ++it) {
    f32x4 fb[8];
#pragma unroll
    for (int p = 0; p < 8; ++p) fb[p] = *(const f32x4*)(bPtr + (size_t)p * N);
    bPtr += (size_t)64 * N;
    uint4 wb[4];
#pragma unroll
    for (int j = 0; j < 4; ++j) {
      uint4 u;
      u.x = packbf(fb[0][j], fb[1][j]); u.y = packbf(fb[2][j], fb[3][j]);
      u.z = packbf(fb[4][j], fb[5][j]); u.w = packbf(fb[6][j], fb[7][j]);
      wb[j] = u;
    }

    __syncthreads();  // prior iter's LDS reads complete
#pragma unroll
    for (int i = 0; i < 4; ++i)
      load_lds16(gA + (size_t)i * 32 * K, &As[lbase + i * 32 * 64]);
    gA += 64;
#pragma unroll
    for (int j = 0; j < 4; ++j)
      *(uint4*)&Bs[(bn + j) * 88 + (bkb >> 3) * 8] = wb[j];
    __syncthreads();  // drains DMA (vmcnt) + ds_writes

#pragma unroll
    for (int kk = 0; kk < 64; kk += 32) {
      const int coff = ((quad + (kk >> 3)) ^ lxor) * 8;
      bf16x8 af[4], bfr[4];
#pragma unroll
      for (int i = 0; i < 4; ++i)
        af[i] = *reinterpret_cast<const bf16x8*>(&As[arowb + i * 16 * 64 + coff]);
#pragma unroll
      for (int j = 0; j < 4; ++j)
        bfr[j] = *reinterpret_cast<const bf16x8*>(&Bs[browb + j * 16 * 88 + quad * 8 + kk]);
#pragma unroll
      for (int i = 0; i < 4; ++i)
#pragma unroll
        for (int j = 0; j < 4; ++j)
          acc[i][j] = __builtin_amdgcn_mfma_f32_16x16x32_bf16(af[i], bfr[j], acc[i][j], 0, 0, 0);
    }
  }

  __syncthreads();
  unsigned short* scr = (wave < 2 ? As : Bs) + (wave & 1) * 2304;
  const int lc = lane & 15;
  const int erow = lane >> 3;
  const int ecol = (lane & 7) * 8;
  unsigned short* Cbase = C + (size_t)(m0 + wm * 64) * N + n0 + wn * 64;
#pragma unroll
  for (int h2 = 0; h2 < 2; ++h2) {
#pragma unroll
    for (int j = 0; j < 4; ++j) {
      float bj = bias[n0 + wn * 64 + j * 16 + lc];
#pragma unroll
      for (int ii = 0; ii < 2; ++ii) {
        int i = h2 * 2 + ii;
#pragma unroll
        for (int rr = 0; rr < 4; ++rr) {
          float v = acc[i][j][rr] + bj;
          scr[(ii * 16 + quad * 4 + rr) * 72 + j * 16 + lc] = f2bf(v);
        }
      }
    }
    __asm__ volatile("s_waitcnt lgkmcnt(0)" ::: "memory");
#pragma unroll
    for (int p = 0; p < 4; ++p) {
      uint4 v = *(const uint4*)&scr[(p * 8 + erow) * 72 + ecol];
      *(uint4*)&Cbase[(size_t)(h2 * 32 + p * 8 + erow) * N + ecol] = v;
    }
  }
}

// ---------------- 5. combine: gate-weighted gather (bf16 expert out) ------------
__global__ void combine_kernel(const unsigned short* __restrict__ outb,
                               const int* __restrict__ tok_e, const int* __restrict__ tok_loc,
                               const float* __restrict__ tok_g, float* __restrict__ y) {
  const int t = blockIdx.x;
  const int tid = threadIdx.x;  // 0..255, 4 bf16 each
  int e0 = tok_e[2 * t], e1 = tok_e[2 * t + 1];
  int l0 = tok_loc[2 * t], l1 = tok_loc[2 * t + 1];
  float g0 = tok_g[2 * t], g1 = tok_g[2 * t + 1];
  float ax = 0.f, ay = 0.f, az = 0.f, aw = 0.f;
  if (l0 >= 0) {
    uint2 u = ((const uint2*)(outb + ((size_t)e0 * CAP + l0) * DIM))[tid];
    ax += g0 * bf2f(u.x & 0xffffu); ay += g0 * __uint_as_float(u.x & 0xffff0000u);
    az += g0 * bf2f(u.y & 0xffffu); aw += g0 * __uint_as_float(u.y & 0xffff0000u);
  }
  if (l1 >= 0) {
    uint2 u = ((const uint2*)(outb + ((size_t)e1 * CAP + l1) * DIM))[tid];
    ax += g1 * bf2f(u.x & 0xffffu); ay += g1 * __uint_as_float(u.x & 0xffff0000u);
    az += g1 * bf2f(u.y & 0xffffu); aw += g1 * __uint_as_float(u.y & 0xffff0000u);
  }
  float4 o; o.x = ax; o.y = ay; o.z = az; o.w = aw;
  ((float4*)(y + (size_t)t * DIM))[tid] = o;
}

extern "C" void kernel_launch(void* const* d_in, const int* in_sizes, int n_in,
                              void* d_out, int out_size, void* d_ws, size_t ws_size,
                              hipStream_t stream) {
  const float* x  = (const float*)d_in[0];
  const float* wg = (const float*)d_in[1];
  const float* w1 = (const float*)d_in[2];
  const float* b1 = (const float*)d_in[3];
  const float* w2 = (const float*)d_in[4];
  const float* b2 = (const float*)d_in[5];
  float* y = (float*)d_out;

  char* ws = (char*)d_ws;
  int*   tok_e    = (int*)(ws);
  int*   tok_loc  = (int*)(ws + 32768);
  float* tok_g    = (float*)(ws + 65536);
  int*   slot_map = (int*)(ws + 98304);
  unsigned short* h    = (unsigned short*)(ws + 131072);                   // 64 MiB
  unsigned short* outb = (unsigned short*)(ws + 131072 + (64ull << 20));   // 16 MiB
  // total: 80 MiB + 128 KiB

  gating_kernel<<<NTOK, 64, 0, stream>>>(x, wg, tok_e, tok_g);
  scan_kernel<<<1, 256, 0, stream>>>(tok_e, tok_loc, slot_map);
  // h = relu(gather(x) @ w1 + b1): M=1024, N=4096, K=1024
  gemm1_kernel<8, 32><<<NEXP * 8 * 32, 256, 0, stream>>>(x, slot_map, w1, b1, h);
  // out = h @ w2 + b2: M=1024, N=1024, K=4096
  gemm2_kernel<8, 8><<<NEXP * 8 * 8, 256, 0, stream>>>(h, w2, b2, outb);
  combine_kernel<<<NTOK, 256, 0, stream>>>(outb, tok_e, tok_loc, tok_g, y);
}